// Round 7
// baseline (233.879 us; speedup 1.0000x reference)
//
#include <hip/hip_runtime.h>
#include <math.h>

#define BATCH 8
#define SEQ   2048
#define DIM   1024
#define HD    64
#define NROWS (BATCH * SEQ)   // 16384
#define CHUNK 512
#define NCHUNK 4              // SEQ / CHUNK
#define QTILE 128             // q rows per attention block
#define NQT   (SEQ / QTILE)   // 16
#define QSCALE 0.1803368801f  // 0.125 * log2(e): folded into Q so P = exp2(QK^T)

typedef __attribute__((ext_vector_type(8))) short bf16x8;  // 8 bf16 = 4 VGPRs
typedef __attribute__((ext_vector_type(4))) float f32x4;

__device__ __forceinline__ unsigned short f2bf(float f) {
    unsigned u = __float_as_uint(f);
    u = (u + 0x7FFFu + ((u >> 16) & 1u)) >> 16;   // RNE
    return (unsigned short)u;
}
// cheap half-up rounding (2 ops)
__device__ __forceinline__ unsigned short f2bf_hu(float f) {
    return (unsigned short)((__float_as_uint(f) + 0x8000u) >> 16);
}
__device__ __forceinline__ float fast_exp2(float x) {
#if __has_builtin(__builtin_amdgcn_exp2f)
    return __builtin_amdgcn_exp2f(x);
#else
    return exp2f(x);
#endif
}

// async global -> LDS DMA, 16 B per lane.  LDS dest = wave-uniform base + lane*16.
__device__ __forceinline__ void gld_lds16(const void* g, void* l) {
    __builtin_amdgcn_global_load_lds(
        (const __attribute__((address_space(1))) void*)g,
        (__attribute__((address_space(3))) void*)l, 16, 0, 0);
}

// pack 8 fp32 -> 8 bf16 (half-up) as one uint4
__device__ __forceinline__ uint4 pack_bf16x8(float4 a, float4 b) {
    uint4 o;
    o.x = ((__float_as_uint(a.x) + 0x8000u) >> 16) | ((__float_as_uint(a.y) + 0x8000u) & 0xFFFF0000u);
    o.y = ((__float_as_uint(a.z) + 0x8000u) >> 16) | ((__float_as_uint(a.w) + 0x8000u) & 0xFFFF0000u);
    o.z = ((__float_as_uint(b.x) + 0x8000u) >> 16) | ((__float_as_uint(b.y) + 0x8000u) & 0xFFFF0000u);
    o.w = ((__float_as_uint(b.z) + 0x8000u) >> 16) | ((__float_as_uint(b.w) + 0x8000u) & 0xFFFF0000u);
    return o;
}

#define CFENCE() asm volatile("" ::: "memory")
#define RAW_BAR() do { CFENCE(); __builtin_amdgcn_s_barrier(); CFENCE(); } while (0)

// Heavy-first (c,qt) schedule for attn: 28 8-tile chunks per batch dispatch
// first (all 256 CUs start heavy), then 6/4/2-tile chunks backfill.
// Entry = (qt << 2) | c.
__device__ __constant__ unsigned char ATTN_MAP[40] = {
    // 8-tile: c=0 qt=3..15
    12, 16, 20, 24, 28, 32, 36, 40, 44, 48, 52, 56, 60,
    // 8-tile: c=1 qt=7..15
    29, 33, 37, 41, 45, 49, 53, 57, 61,
    // 8-tile: c=2 qt=11..15
    46, 50, 54, 58, 62,
    // 8-tile: c=3 qt=15
    63,
    // 6-tile: (0,2) (1,6) (2,10) (3,14)
    8, 25, 42, 59,
    // 4-tile: (0,1) (1,5) (2,9) (3,13)
    4, 21, 38, 55,
    // 2-tile: (0,0) (1,4) (2,8) (3,12)
    0, 17, 34, 51
};

// ---------------------------------------------------------------------------
// prep_w: Wt[mat][n][k] (bf16) <- W[k][n] (fp32).  grid (16,3), block 256.
// Also zeroes the attn completion counters (workspace is poisoned each run).
// ---------------------------------------------------------------------------
__global__ __launch_bounds__(256)
void prep_w_kernel(const float* __restrict__ Wq, const float* __restrict__ Wk,
                   const float* __restrict__ Wv, unsigned short* __restrict__ Wt,
                   unsigned* __restrict__ Cnt)
{
    const int mat = blockIdx.y;
    const float* __restrict__ W = (mat == 0) ? Wq : (mat == 1) ? Wk : Wv;
    const int k0 = blockIdx.x * 64;
    __shared__ float T[64][65];
    const int t = threadIdx.x;
    if (blockIdx.x == 0 && mat == 0 && t < BATCH * NQT)
        Cnt[t] = 0u;
    #pragma unroll
    for (int i = 0; i < 16; ++i) {
        const int idx = t + i * 256;
        T[idx >> 6][idx & 63] = W[(size_t)(k0 + (idx >> 6)) * HD + (idx & 63)];
    }
    __syncthreads();
    const int n = t >> 2;
    const int c = t & 3;
    union { unsigned short h[16]; uint4 v[2]; } buf;
    #pragma unroll
    for (int j = 0; j < 16; ++j) buf.h[j] = f2bf(T[c * 16 + j][n]);
    unsigned short* dst = Wt + ((size_t)mat * HD + n) * DIM + k0 + c * 16;
    *(uint4*)dst       = buf.v[0];
    *(uint4*)(dst + 8) = buf.v[1];
}

// ---------------------------------------------------------------------------
// qkv_mfma v4: tile 64 rows x 192 cols (grid 256), BK=64, double-buffered LDS
// (64 KB), raw s_barrier + counted vmcnt(2).  12 waves (768 thr):
// wave w -> mat = w>>2 (0=Q,1=K,2=V), row quarter wr = w&3.
// ---------------------------------------------------------------------------
__global__ __launch_bounds__(768)
void qkv_mfma_kernel(const float* __restrict__ x,
                     const unsigned short* __restrict__ Wt,
                     const float* __restrict__ bq, const float* __restrict__ bk,
                     const float* __restrict__ bv,
                     unsigned short* __restrict__ Qg,
                     unsigned short* __restrict__ Kg,
                     unsigned short* __restrict__ Vtg)
{
    __shared__ unsigned short Xs[2][64][64];    // 16 KB bf16, swizzled chunks (key r&7)
    __shared__ unsigned short Ws[2][192][64];   // 48 KB bf16, swizzled chunks (key r&7)

    const int t    = threadIdx.x;
    const int lane = t & 63;
    const int w    = t >> 6;         // 0..11
    const int col  = lane & 15;
    const int quad = lane >> 4;
    const int mat  = w >> 2;         // 0=Q, 1=K, 2=V
    const int wr   = w & 3;          // 16-row quarter
    const int row0 = blockIdx.x * 64;

    const int r8  = lane >> 3;       // W: row within an 8-row DMA call
    const int ch8 = lane & 7;        // W: 16B chunk within row (8 chunks)
    const int wswz = (ch8 ^ r8) * 8; // W source swizzle (rbase ≡ 0 mod 8)

    f32x4 acc[4];
    #pragma unroll
    for (int i = 0; i < 4; ++i) acc[i] = (f32x4){0.f, 0.f, 0.f, 0.f};

    // X staging: threads 0..511 own (row xr, 8-float chunk xc0)
    const int xr  = t >> 3;          // 0..63
    const int xc0 = t & 7;           // 0..7
    const float* __restrict__ xrow = &x[(size_t)(row0 + xr) * DIM];

    auto stageW = [&](int it, int bb) {   // 2 calls x 8 rows = 16 rows per wave
        const int k0 = it * 64;
        #pragma unroll
        for (int ii = 0; ii < 2; ++ii) {
            const int rbase = w * 16 + ii * 8;
            gld_lds16(&Wt[(size_t)(rbase + r8) * DIM + k0 + wswz], &Ws[bb][rbase][0]);
        }
    };
    auto computeT = [&](int bb) {
        #pragma unroll
        for (int ks = 0; ks < 2; ++ks) {
            const int fswz = ((ks * 4 + quad) ^ (col & 7)) * 8;
            const bf16x8 a = *(const bf16x8*)&Xs[bb][wr * 16 + col][fswz];
            #pragma unroll
            for (int nt = 0; nt < 4; ++nt) {
                const bf16x8 b = *(const bf16x8*)&Ws[bb][mat * 64 + nt * 16 + col][fswz];
                acc[nt] = __builtin_amdgcn_mfma_f32_16x16x32_bf16(a, b, acc[nt], 0, 0, 0);
            }
        }
    };

    // ---- prologue: stage tile 0; prefetch X(1) into regs ----
    float4 xa, xb;
    stageW(0, 0);
    if (t < 512) {
        xa = *(const float4*)(xrow + xc0 * 8);
        xb = *(const float4*)(xrow + xc0 * 8 + 4);
    }
    asm volatile("s_waitcnt vmcnt(0)" ::: "memory");
    if (t < 512) {
        *(uint4*)&Xs[0][xr][(xc0 ^ (xr & 7)) * 8] = pack_bf16x8(xa, xb);
        xa = *(const float4*)(xrow + 64 + xc0 * 8);
        xb = *(const float4*)(xrow + 64 + xc0 * 8 + 4);
    }

    int buf = 0;
    for (int it = 0; it < 16; ++it) {
        RAW_BAR();                    // [A] all waves done reading buf^1
        if (it < 15) {
            stageW(it + 1, buf ^ 1);  // prefetch next W tile (stays in flight)
            // drains W(it) + X-loads(it+1); leaves W(it+1) in flight
            asm volatile("s_waitcnt vmcnt(2)" ::: "memory");
            if (t < 512) {
                *(uint4*)&Xs[buf ^ 1][xr][(xc0 ^ (xr & 7)) * 8] = pack_bf16x8(xa, xb);
                if (it < 14) {
                    const float* xp = xrow + (it + 2) * 64;
                    xa = *(const float4*)(xp + xc0 * 8);
                    xb = *(const float4*)(xp + xc0 * 8 + 4);
                }
            }
        } else {
            asm volatile("s_waitcnt vmcnt(0)" ::: "memory");   // drain last W
        }
        RAW_BAR();                    // [D] tile `it` fully in LDS
        computeT(buf);                // ds_read + 8 MFMA per wave
        buf ^= 1;
    }

    // Epilogue.  C layout: col = lane&15, row = quad*4 + r.
    const int b    = row0 / SEQ;
    const int s0   = (row0 % SEQ) + wr * 16 + quad * 4;
    const int grow = row0 + wr * 16 + quad * 4;
    const float* __restrict__ bias = (mat == 0) ? bq : (mat == 1) ? bk : bv;
    const float oscale = (mat == 0) ? QSCALE : 1.0f;   // fold softmax scale into Q
    #pragma unroll
    for (int nt = 0; nt < 4; ++nt) {
        const int nn = nt * 16 + col;
        const float bvv = bias[nn];
        if (mat < 2) {
            unsigned short* __restrict__ o = (mat == 0) ? Qg : Kg;
            #pragma unroll
            for (int r = 0; r < 4; ++r)
                o[(size_t)(grow + r) * HD + nn] = f2bf((acc[nt][r] + bvv) * oscale);
        } else {
            const unsigned lo = (unsigned)f2bf(acc[nt][0] + bvv) | ((unsigned)f2bf(acc[nt][1] + bvv) << 16);
            const unsigned hi = (unsigned)f2bf(acc[nt][2] + bvv) | ((unsigned)f2bf(acc[nt][3] + bvv) << 16);
            *(uint2*)&Vtg[((size_t)b * HD + nn) * SEQ + s0] = make_uint2(lo, hi);
        }
    }
}

// ---------------------------------------------------------------------------
// attn_part v3: split-key flash attention (QTILE=128, CHUNK=512), 8 waves,
// double-buffered K/V with raw s_barrier + counted vmcnt(2) -- round-5
// structure -- plus:
//  (1) heavy-first dispatch via ATTN_MAP (8-tile chunks start first; light
//      chunks backfill), cutting the makespan of the 320-block grid;
//  (2) fused combine: partials + threadfence + per-(b,qt) counter; the LAST
//      chunk-block re-reads partials with agent-scope loads (coherent point;
//      protocol validated in round 1) and writes normalized fp32 out.
// grid (8, 40): x = batch (XCD-aligned), y = schedule slot.  LDS 52 KB.
// ---------------------------------------------------------------------------
__global__ __launch_bounds__(512)
void attn_part_kernel(const unsigned short* __restrict__ Qg,
                      const unsigned short* __restrict__ Kg,
                      const unsigned short* __restrict__ Vtg,
                      unsigned short* __restrict__ Opart,  // [512][128][64] bf16
                      float* __restrict__ Lsum,            // [512][128]
                      unsigned* __restrict__ Cnt,          // [128], zeroed by prep
                      float* __restrict__ out)             // [16384][64] f32
{
    const int b = blockIdx.x;
    const int code = ATTN_MAP[blockIdx.y];
    const int qt = code >> 2;
    const int c  = code & 3;

    __shared__ unsigned short Ks[2][64][64];  // [key][d], swizzled (key r&7)
    __shared__ unsigned short Vs[2][64][64];  // [d][key], swizzled
    __shared__ unsigned short Ps[8][16][76];  // per-wave P, A layout [m][key]
    __shared__ int isLast;

    const int t    = threadIdx.x;
    const int w    = t >> 6;         // 0..7
    const int lane = t & 63;
    const int col  = lane & 15;
    const int quad = lane >> 4;
    const int q0w  = qt * QTILE + w * 16;
    const size_t gq = (size_t)b * SEQ + q0w;

    const bf16x8 aq0 = *(const bf16x8*)&Qg[(gq + col) * HD + quad * 8];
    const bf16x8 aq1 = *(const bf16x8*)&Qg[(gq + col) * HD + 32 + quad * 8];

    f32x4 oacc[4];
    #pragma unroll
    for (int n = 0; n < 4; ++n) oacc[n] = (f32x4){0.f, 0.f, 0.f, 0.f};
    float lpart[4] = {0.f, 0.f, 0.f, 0.f};   // per-lane partial denominators

    const int kbeg   = c * CHUNK;
    const int kend   = min((c + 1) * CHUNK, (qt + 1) * QTILE);
    const int ntiles = (kend - kbeg + 63) >> 6;   // 2..8

    const int r8 = lane >> 3, ch = lane & 7;
    const int swzr = (ch ^ r8) * 8;
    const unsigned short* kgb = Kg  + (size_t)b * SEQ * HD;
    const unsigned short* vgb = Vtg + (size_t)b * HD * SEQ;

    // stage K tile (8 KB) + V^T tile (8 KB): 8 waves x (1 K + 1 V call) x 8 rows
    auto stageKV = [&](int it, int bb) {
        const int j0 = kbeg + it * 64;
        const int rb = w * 8;
        gld_lds16(&kgb[(size_t)(j0 + rb + r8) * HD + swzr], &Ks[bb][rb][0]);
        gld_lds16(&vgb[(size_t)(rb + r8) * SEQ + j0 + swzr], &Vs[bb][rb][0]);
    };

    stageKV(0, 0);   // prologue (completion enforced at it=0's vmcnt)

    int bufb = 0;
    for (int it = 0; it < ntiles; ++it) {
        RAW_BAR();                      // [A] readers of buf^1 done (prev compute)
        if (it + 1 < ntiles) {
            stageKV(it + 1, bufb ^ 1);  // prefetch next tile (stays in flight)
            // per-wave: 2 outstanding for tile it + 2 for it+1 (+Q loads at it=0)
            asm volatile("s_waitcnt vmcnt(2)" ::: "memory");
        } else {
            asm volatile("s_waitcnt vmcnt(0)" ::: "memory");
        }
        RAW_BAR();                      // [D] tile `it` fully in LDS
        const int j0 = kbeg + it * 64;

        if (j0 <= q0w + 15) {   // wave-uniform: skip fully-masked tiles
            // scores (log2 domain: Q carries 0.125*log2e)
            f32x4 scv[4];
            #pragma unroll
            for (int nt = 0; nt < 4; ++nt) {
                const int sw0 = (quad ^ (col & 7)) * 8;
                const int sw1 = ((4 + quad) ^ (col & 7)) * 8;
                const bf16x8 bk0 = *(const bf16x8*)&Ks[bufb][nt * 16 + col][sw0];
                const bf16x8 bk1 = *(const bf16x8*)&Ks[bufb][nt * 16 + col][sw1];
                f32x4 s = __builtin_amdgcn_mfma_f32_16x16x32_bf16(aq0, bk0, (f32x4){0.f,0.f,0.f,0.f}, 0, 0, 0);
                s = __builtin_amdgcn_mfma_f32_16x16x32_bf16(aq1, bk1, s, 0, 0, 0);
                scv[nt] = s;
            }
            const bool needmask = (j0 + 63 > q0w);
            #pragma unroll
            for (int r = 0; r < 4; ++r) {
                const int row = q0w + quad * 4 + r;
                #pragma unroll
                for (int nt = 0; nt < 4; ++nt) {
                    float s = scv[nt][r];
                    if (needmask)
                        s = (j0 + nt * 16 + col <= row) ? s : -INFINITY;
                    const float p = fast_exp2(s);   // exp2(-inf) = 0 handles mask
                    lpart[r] += p;
                    Ps[w][quad * 4 + r][nt * 16 + col] = f2bf_hu(p);  // same-wave LDS
                }
            }
            // PV: O += P V
            #pragma unroll
            for (int ks = 0; ks < 2; ++ks) {
                const bf16x8 ap = *(const bf16x8*)&Ps[w][col][ks * 32 + quad * 8];
                const int fswz = ((ks * 4 + quad) ^ (col & 7)) * 8;
                #pragma unroll
                for (int n = 0; n < 4; ++n) {
                    const bf16x8 bv2 = *(const bf16x8*)&Vs[bufb][n * 16 + col][fswz];
                    oacc[n] = __builtin_amdgcn_mfma_f32_16x16x32_bf16(ap, bv2, oacc[n], 0, 0, 0);
                }
            }
        }
        bufb ^= 1;
    }

    // deferred 16-lane reduction of the denominators (once per kernel)
    #pragma unroll
    for (int r = 0; r < 4; ++r) {
        #pragma unroll
        for (int off = 1; off < 16; off <<= 1)
            lpart[r] += __shfl_xor(lpart[r], off, 64);
    }

    // epilogue: un-normalized bf16 partials + fp32 denominators
    const int blk = (b * NQT + qt) * NCHUNK + c;
    unsigned short* Ob = Opart + (size_t)blk * (QTILE * HD);
    #pragma unroll
    for (int n = 0; n < 4; ++n)
        #pragma unroll
        for (int r = 0; r < 4; ++r)
            Ob[(w * 16 + quad * 4 + r) * HD + n * 16 + col] = f2bf(oacc[n][r]);
    if (col == 0) {
        float* lb = Lsum + (size_t)blk * QTILE + w * 16;
        #pragma unroll
        for (int r = 0; r < 4; ++r)
            lb[quad * 4 + r] = lpart[r];
    }

    // completion protocol: my stores -> device fence -> block barrier -> count
    __threadfence();
    __syncthreads();
    const int nchunks = (qt >> 2) + 1;   // chunk-blocks covering this q-tile
    if (t == 0)
        isLast = (atomicAdd(&Cnt[b * NQT + qt], 1u) == (unsigned)(nchunks - 1));
    __syncthreads();
    if (!isLast) return;
    __threadfence();   // acquire: all other chunks' partials now visible

    // finisher: combine <=4 chunks for 128 rows x 64 dims, write fp32 out.
    // Agent-scope relaxed atomic loads read the coherent point (bypass the
    // possibly-stale XCD L2) -- same path as the round-1 finisher (passed).
    const int r   = t >> 2;            // 0..127 (q row within tile)
    const int d0  = (t & 3) * 16;      // 16 dims per thread
    const int blk0 = (b * NQT + qt) * NCHUNK;
    const size_t grow = (size_t)b * SEQ + qt * QTILE + r;
    float L = 0.f;
    float a[16];
    #pragma unroll
    for (int j = 0; j < 16; ++j) a[j] = 0.f;
    for (int cc = 0; cc < nchunks; ++cc) {
        L += __hip_atomic_load(&Lsum[(size_t)(blk0 + cc) * QTILE + r],
                               __ATOMIC_RELAXED, __HIP_MEMORY_SCOPE_AGENT);
        const unsigned short* Op = Opart + (size_t)(blk0 + cc) * (QTILE * HD) + r * HD + d0;
        #pragma unroll
        for (int j = 0; j < 4; ++j) {
            const unsigned long long u = __hip_atomic_load(
                (const unsigned long long*)(Op + j * 4),
                __ATOMIC_RELAXED, __HIP_MEMORY_SCOPE_AGENT);
            a[j * 4 + 0] += __uint_as_float((unsigned)(u      ) << 16);
            a[j * 4 + 1] += __uint_as_float((unsigned)(u      ) & 0xFFFF0000u);
            a[j * 4 + 2] += __uint_as_float((unsigned)(u >> 32) << 16);
            a[j * 4 + 3] += __uint_as_float((unsigned)(u >> 32) & 0xFFFF0000u);
        }
    }
    const float rL = 1.0f / L;
    float4* op = (float4*)&out[grow * HD + d0];
    #pragma unroll
    for (int j = 0; j < 4; ++j)
        op[j] = (float4){a[j*4] * rL, a[j*4+1] * rL, a[j*4+2] * rL, a[j*4+3] * rL};
}

// ---------------------------------------------------------------------------
extern "C" void kernel_launch(void* const* d_in, const int* in_sizes, int n_in,
                              void* d_out, int out_size, void* d_ws, size_t ws_size,
                              hipStream_t stream) {
    const float* x  = (const float*)d_in[0];
    const float* Wq = (const float*)d_in[1];
    const float* bq = (const float*)d_in[2];
    const float* Wk = (const float*)d_in[3];
    const float* bk = (const float*)d_in[4];
    const float* Wv = (const float*)d_in[5];
    const float* bv = (const float*)d_in[6];
    float* out = (float*)d_out;

    unsigned short* Wt    = (unsigned short*)d_ws;        // [3][64][1024] bf16
    unsigned short* Qg    = Wt + (size_t)3 * HD * DIM;    // [16384][64] bf16 (pre-scaled)
    unsigned short* Kg    = Qg + (size_t)NROWS * HD;      // [16384][64] bf16
    unsigned short* Vtg   = Kg + (size_t)NROWS * HD;      // [8][64][2048] bf16
    unsigned short* Opart = Vtg + (size_t)BATCH * HD * SEQ;               // [512][128][64] bf16
    float* Lsum = (float*)(Opart + (size_t)BATCH * NQT * NCHUNK * QTILE * HD);  // [512][128]
    unsigned* Cnt = (unsigned*)(Lsum + (size_t)BATCH * NQT * NCHUNK * QTILE);   // [128] u32

    prep_w_kernel<<<dim3(16, 3), 256, 0, stream>>>(Wq, Wk, Wv, Wt, Cnt);
    qkv_mfma_kernel<<<dim3(NROWS / 64), 768, 0, stream>>>(x, Wt, bq, bk, bv, Qg, Kg, Vtg);
    attn_part_kernel<<<dim3(8, 40), 512, 0, stream>>>(Qg, Kg, Vtg, Opart, Lsum, Cnt, out);
}

// Round 8
// 135.670 us; speedup vs baseline: 1.7239x; 1.7239x over previous
//
#include <hip/hip_runtime.h>
#include <math.h>

#define BATCH 8
#define SEQ   2048
#define DIM   1024
#define HD    64
#define NROWS (BATCH * SEQ)   // 16384
#define CHUNK 512
#define NCHUNK 4              // SEQ / CHUNK
#define QTILE 128             // q rows per attention block
#define NQT   (SEQ / QTILE)   // 16
#define QSCALE 0.1803368801f  // 0.125 * log2(e): folded into Q so P = exp2(QK^T)

typedef __attribute__((ext_vector_type(8))) short bf16x8;  // 8 bf16 = 4 VGPRs
typedef __attribute__((ext_vector_type(4))) float f32x4;

__device__ __forceinline__ unsigned short f2bf(float f) {
    unsigned u = __float_as_uint(f);
    u = (u + 0x7FFFu + ((u >> 16) & 1u)) >> 16;   // RNE
    return (unsigned short)u;
}
// cheap half-up rounding (2 ops)
__device__ __forceinline__ unsigned short f2bf_hu(float f) {
    return (unsigned short)((__float_as_uint(f) + 0x8000u) >> 16);
}
__device__ __forceinline__ float fast_exp2(float x) {
#if __has_builtin(__builtin_amdgcn_exp2f)
    return __builtin_amdgcn_exp2f(x);
#else
    return exp2f(x);
#endif
}

// async global -> LDS DMA, 16 B per lane.  LDS dest = wave-uniform base + lane*16.
__device__ __forceinline__ void gld_lds16(const void* g, void* l) {
    __builtin_amdgcn_global_load_lds(
        (const __attribute__((address_space(1))) void*)g,
        (__attribute__((address_space(3))) void*)l, 16, 0, 0);
}

// pack 8 fp32 -> 8 bf16 (half-up) as one uint4
__device__ __forceinline__ uint4 pack_bf16x8(float4 a, float4 b) {
    uint4 o;
    o.x = ((__float_as_uint(a.x) + 0x8000u) >> 16) | ((__float_as_uint(a.y) + 0x8000u) & 0xFFFF0000u);
    o.y = ((__float_as_uint(a.z) + 0x8000u) >> 16) | ((__float_as_uint(a.w) + 0x8000u) & 0xFFFF0000u);
    o.z = ((__float_as_uint(b.x) + 0x8000u) >> 16) | ((__float_as_uint(b.y) + 0x8000u) & 0xFFFF0000u);
    o.w = ((__float_as_uint(b.z) + 0x8000u) >> 16) | ((__float_as_uint(b.w) + 0x8000u) & 0xFFFF0000u);
    return o;
}

#define CFENCE() asm volatile("" ::: "memory")
#define RAW_BAR() do { CFENCE(); __builtin_amdgcn_s_barrier(); CFENCE(); } while (0)

// Heavy-first (c,qt) schedule for attn (validated for correctness in r7):
// 28 8-tile chunks per batch dispatch first, light chunks backfill.
// Entry = (qt << 2) | c.
__device__ __constant__ unsigned char ATTN_MAP[40] = {
    12, 16, 20, 24, 28, 32, 36, 40, 44, 48, 52, 56, 60,   // 8-tile c=0
    29, 33, 37, 41, 45, 49, 53, 57, 61,                     // 8-tile c=1
    46, 50, 54, 58, 62,                                     // 8-tile c=2
    63,                                                     // 8-tile c=3
    8, 25, 42, 59,                                          // 6-tile
    4, 21, 38, 55,                                          // 4-tile
    0, 17, 34, 51                                           // 2-tile
};

// ---------------------------------------------------------------------------
// prep_w: Wt[mat][n][k] (bf16) <- W[k][n] (fp32).  grid (16,3), block 256.
// ---------------------------------------------------------------------------
__global__ __launch_bounds__(256)
void prep_w_kernel(const float* __restrict__ Wq, const float* __restrict__ Wk,
                   const float* __restrict__ Wv, unsigned short* __restrict__ Wt)
{
    const int mat = blockIdx.y;
    const float* __restrict__ W = (mat == 0) ? Wq : (mat == 1) ? Wk : Wv;
    const int k0 = blockIdx.x * 64;
    __shared__ float T[64][65];
    const int t = threadIdx.x;
    #pragma unroll
    for (int i = 0; i < 16; ++i) {
        const int idx = t + i * 256;
        T[idx >> 6][idx & 63] = W[(size_t)(k0 + (idx >> 6)) * HD + (idx & 63)];
    }
    __syncthreads();
    const int n = t >> 2;
    const int c = t & 3;
    union { unsigned short h[16]; uint4 v[2]; } buf;
    #pragma unroll
    for (int j = 0; j < 16; ++j) buf.h[j] = f2bf(T[c * 16 + j][n]);
    unsigned short* dst = Wt + ((size_t)mat * HD + n) * DIM + k0 + c * 16;
    *(uint4*)dst       = buf.v[0];
    *(uint4*)(dst + 8) = buf.v[1];
}

// ---------------------------------------------------------------------------
// qkv_mfma v5: tile 64 rows x 192 cols (grid 256), BK=64, double-buffered,
// ONE barrier per iteration: stage(it+1) issues at iteration top (safe: the
// previous barrier retired all readers of that buffer), compute(it) runs,
// then a post-compute counted wait drains stage(it+1) (L2-resident W lands
// under compute) while the 2-deep x reg-prefetch stays uncounted in flight.
// 12 waves (768 thr): wave w -> mat = w>>2, row quarter wr = w&3.
// Per-iter floor = x HBM stream (16 KB/block/iter ~ 1600 cyc).
// ---------------------------------------------------------------------------
__global__ __launch_bounds__(768)
void qkv_mfma_kernel(const float* __restrict__ x,
                     const unsigned short* __restrict__ Wt,
                     const float* __restrict__ bq, const float* __restrict__ bk,
                     const float* __restrict__ bv,
                     unsigned short* __restrict__ Qg,
                     unsigned short* __restrict__ Kg,
                     unsigned short* __restrict__ Vtg)
{
    __shared__ unsigned short Xs[2][64][64];    // 16 KB bf16, swizzled chunks (key r&7)
    __shared__ unsigned short Ws[2][192][64];   // 48 KB bf16, swizzled chunks (key r&7)

    const int t    = threadIdx.x;
    const int lane = t & 63;
    const int w    = t >> 6;         // 0..11
    const int col  = lane & 15;
    const int quad = lane >> 4;
    const int mat  = w >> 2;         // 0=Q, 1=K, 2=V
    const int wr   = w & 3;          // 16-row quarter
    const int row0 = blockIdx.x * 64;

    const int r8  = lane >> 3;       // W: row within an 8-row DMA call
    const int ch8 = lane & 7;        // W: 16B chunk within row (8 chunks)
    const int wswz = (ch8 ^ r8) * 8; // W source swizzle (rbase ≡ 0 mod 8)

    f32x4 acc[4];
    #pragma unroll
    for (int i = 0; i < 4; ++i) acc[i] = (f32x4){0.f, 0.f, 0.f, 0.f};

    // X staging: threads 0..511 own (row xr, 8-float chunk xc0)
    const int xr  = t >> 3;          // 0..63
    const int xc0 = t & 7;           // 0..7
    const float* __restrict__ xrow = &x[(size_t)(row0 + xr) * DIM];

    auto stageW = [&](int it, int bb) {   // 2 calls x 8 rows = 16 rows per wave
        const int k0 = it * 64;
        #pragma unroll
        for (int ii = 0; ii < 2; ++ii) {
            const int rbase = w * 16 + ii * 8;
            gld_lds16(&Wt[(size_t)(rbase + r8) * DIM + k0 + wswz], &Ws[bb][rbase][0]);
        }
    };
    auto computeT = [&](int bb) {
        #pragma unroll
        for (int ks = 0; ks < 2; ++ks) {
            const int fswz = ((ks * 4 + quad) ^ (col & 7)) * 8;
            const bf16x8 a = *(const bf16x8*)&Xs[bb][wr * 16 + col][fswz];
            #pragma unroll
            for (int nt = 0; nt < 4; ++nt) {
                const bf16x8 b = *(const bf16x8*)&Ws[bb][mat * 64 + nt * 16 + col][fswz];
                acc[nt] = __builtin_amdgcn_mfma_f32_16x16x32_bf16(a, b, acc[nt], 0, 0, 0);
            }
        }
    };

    // ---- prologue: stage tile 0; prefetch x(1) into regs ----
    float4 xa, xb;
    stageW(0, 0);
    if (t < 512) {
        xa = *(const float4*)(xrow + xc0 * 8);
        xb = *(const float4*)(xrow + xc0 * 8 + 4);
    }
    asm volatile("s_waitcnt vmcnt(0)" ::: "memory");
    if (t < 512) {
        *(uint4*)&Xs[0][xr][(xc0 ^ (xr & 7)) * 8] = pack_bf16x8(xa, xb);
        xa = *(const float4*)(xrow + 64 + xc0 * 8);
        xb = *(const float4*)(xrow + 64 + xc0 * 8 + 4);
    }
    asm volatile("s_waitcnt lgkmcnt(0)" ::: "memory");
    RAW_BAR();   // tile 0 fully in LDS

    int buf = 0;
    for (int it = 0; it < 16; ++it) {
        if (it < 15) {
            stageW(it + 1, buf ^ 1);         // W(it+1) DMA: lands under compute
            if (t < 512) {
                // store x(it+1) from regs (loaded 1 HBM-latency+iter ago)
                *(uint4*)&Xs[buf ^ 1][xr][(xc0 ^ (xr & 7)) * 8] = pack_bf16x8(xa, xb);
                if (it < 14) {               // issue x(it+2): 2-deep prefetch
                    const float* xp = xrow + (it + 2) * 64;
                    xa = *(const float4*)(xp + xc0 * 8);
                    xb = *(const float4*)(xp + xc0 * 8 + 4);
                }
            }
        }
        computeT(buf);                       // tile it
        if (it < 15) {
            // post-compute wait: drain W(it+1) (+x-store lgkm), keep x(it+2)
            // in flight.  staging waves have 4 outstanding while it<14
            // (W(it+1) x2 oldest + x(it+2) x2); at it=14 no new x -> drain all.
            if (w < 8 && it < 14)
                asm volatile("s_waitcnt vmcnt(2) lgkmcnt(0)" ::: "memory");
            else
                asm volatile("s_waitcnt vmcnt(0) lgkmcnt(0)" ::: "memory");
            RAW_BAR();                       // single barrier per iteration
        }
        buf ^= 1;
    }

    // Epilogue.  C layout: col = lane&15, row = quad*4 + r.
    const int b    = row0 / SEQ;
    const int s0   = (row0 % SEQ) + wr * 16 + quad * 4;
    const int grow = row0 + wr * 16 + quad * 4;
    const float* __restrict__ bias = (mat == 0) ? bq : (mat == 1) ? bk : bv;
    const float oscale = (mat == 0) ? QSCALE : 1.0f;   // fold softmax scale into Q
    #pragma unroll
    for (int nt = 0; nt < 4; ++nt) {
        const int nn = nt * 16 + col;
        const float bvv = bias[nn];
        if (mat < 2) {
            unsigned short* __restrict__ o = (mat == 0) ? Qg : Kg;
            #pragma unroll
            for (int r = 0; r < 4; ++r)
                o[(size_t)(grow + r) * HD + nn] = f2bf((acc[nt][r] + bvv) * oscale);
        } else {
            const unsigned lo = (unsigned)f2bf(acc[nt][0] + bvv) | ((unsigned)f2bf(acc[nt][1] + bvv) << 16);
            const unsigned hi = (unsigned)f2bf(acc[nt][2] + bvv) | ((unsigned)f2bf(acc[nt][3] + bvv) << 16);
            *(uint2*)&Vtg[((size_t)b * HD + nn) * SEQ + s0] = make_uint2(lo, hi);
        }
    }
}

// ---------------------------------------------------------------------------
// attn_part v4: round-5 split-key flash attention (QTILE=128, CHUNK=512,
// 8 waves, dbuf K/V) with (a) heavy-first dispatch via ATTN_MAP (scheduling
// only -- r7's fence/finisher removed) and (b) ONE barrier per iteration:
// stage(it+1) at iteration top, post-compute vmcnt(0) drains it (K/V are
// L2-resident; latency hides under QK^T/softmax/PV).
// grid (8, 40): x = batch (XCD-aligned), y = schedule slot.  LDS 52 KB.
// ---------------------------------------------------------------------------
__global__ __launch_bounds__(512)
void attn_part_kernel(const unsigned short* __restrict__ Qg,
                      const unsigned short* __restrict__ Kg,
                      const unsigned short* __restrict__ Vtg,
                      unsigned short* __restrict__ Opart,  // [512][128][64] bf16
                      float* __restrict__ Lsum)            // [512][128]
{
    const int b = blockIdx.x;
    const int code = ATTN_MAP[blockIdx.y];
    const int qt = code >> 2;
    const int c  = code & 3;

    __shared__ unsigned short Ks[2][64][64];  // [key][d], swizzled (key r&7)
    __shared__ unsigned short Vs[2][64][64];  // [d][key], swizzled
    __shared__ unsigned short Ps[8][16][76];  // per-wave P, A layout [m][key]

    const int t    = threadIdx.x;
    const int w    = t >> 6;         // 0..7
    const int lane = t & 63;
    const int col  = lane & 15;
    const int quad = lane >> 4;
    const int q0w  = qt * QTILE + w * 16;
    const size_t gq = (size_t)b * SEQ + q0w;

    const bf16x8 aq0 = *(const bf16x8*)&Qg[(gq + col) * HD + quad * 8];
    const bf16x8 aq1 = *(const bf16x8*)&Qg[(gq + col) * HD + 32 + quad * 8];

    f32x4 oacc[4];
    #pragma unroll
    for (int n = 0; n < 4; ++n) oacc[n] = (f32x4){0.f, 0.f, 0.f, 0.f};
    float lpart[4] = {0.f, 0.f, 0.f, 0.f};   // per-lane partial denominators

    const int kbeg   = c * CHUNK;
    const int kend   = min((c + 1) * CHUNK, (qt + 1) * QTILE);
    const int ntiles = (kend - kbeg + 63) >> 6;   // 2..8

    const int r8 = lane >> 3, ch = lane & 7;
    const int swzr = (ch ^ r8) * 8;
    const unsigned short* kgb = Kg  + (size_t)b * SEQ * HD;
    const unsigned short* vgb = Vtg + (size_t)b * HD * SEQ;

    // stage K tile (8 KB) + V^T tile (8 KB): 8 waves x (1 K + 1 V call) x 8 rows
    auto stageKV = [&](int it, int bb) {
        const int j0 = kbeg + it * 64;
        const int rb = w * 8;
        gld_lds16(&kgb[(size_t)(j0 + rb + r8) * HD + swzr], &Ks[bb][rb][0]);
        gld_lds16(&vgb[(size_t)(rb + r8) * SEQ + j0 + swzr], &Vs[bb][rb][0]);
    };

    // prologue: stage tile 0, drain (also retires the Q loads), publish
    stageKV(0, 0);
    asm volatile("s_waitcnt vmcnt(0)" ::: "memory");
    RAW_BAR();

    int bufb = 0;
    for (int it = 0; it < ntiles; ++it) {
        if (it + 1 < ntiles)
            stageKV(it + 1, bufb ^ 1);   // lands under this tile's compute
        const int j0 = kbeg + it * 64;

        if (j0 <= q0w + 15) {   // wave-uniform: skip fully-masked tiles
            // scores (log2 domain: Q carries 0.125*log2e)
            f32x4 scv[4];
            #pragma unroll
            for (int nt = 0; nt < 4; ++nt) {
                const int sw0 = (quad ^ (col & 7)) * 8;
                const int sw1 = ((4 + quad) ^ (col & 7)) * 8;
                const bf16x8 bk0 = *(const bf16x8*)&Ks[bufb][nt * 16 + col][sw0];
                const bf16x8 bk1 = *(const bf16x8*)&Ks[bufb][nt * 16 + col][sw1];
                f32x4 s = __builtin_amdgcn_mfma_f32_16x16x32_bf16(aq0, bk0, (f32x4){0.f,0.f,0.f,0.f}, 0, 0, 0);
                s = __builtin_amdgcn_mfma_f32_16x16x32_bf16(aq1, bk1, s, 0, 0, 0);
                scv[nt] = s;
            }
            const bool needmask = (j0 + 63 > q0w);
            #pragma unroll
            for (int r = 0; r < 4; ++r) {
                const int row = q0w + quad * 4 + r;
                #pragma unroll
                for (int nt = 0; nt < 4; ++nt) {
                    float s = scv[nt][r];
                    if (needmask)
                        s = (j0 + nt * 16 + col <= row) ? s : -INFINITY;
                    const float p = fast_exp2(s);   // exp2(-inf) = 0 handles mask
                    lpart[r] += p;
                    Ps[w][quad * 4 + r][nt * 16 + col] = f2bf_hu(p);  // same-wave LDS
                }
            }
            // PV: O += P V
            #pragma unroll
            for (int ks = 0; ks < 2; ++ks) {
                const bf16x8 ap = *(const bf16x8*)&Ps[w][col][ks * 32 + quad * 8];
                const int fswz = ((ks * 4 + quad) ^ (col & 7)) * 8;
                #pragma unroll
                for (int n = 0; n < 4; ++n) {
                    const bf16x8 bv2 = *(const bf16x8*)&Vs[bufb][n * 16 + col][fswz];
                    oacc[n] = __builtin_amdgcn_mfma_f32_16x16x32_bf16(ap, bv2, oacc[n], 0, 0, 0);
                }
            }
        }
        if (it + 1 < ntiles) {
            // post-compute drain of stage(it+1): L2-resident, mostly landed
            asm volatile("s_waitcnt vmcnt(0) lgkmcnt(0)" ::: "memory");
            RAW_BAR();                   // single barrier per iteration
        }
        bufb ^= 1;
    }

    // deferred 16-lane reduction of the denominators (once per kernel)
    #pragma unroll
    for (int r = 0; r < 4; ++r) {
        #pragma unroll
        for (int off = 1; off < 16; off <<= 1)
            lpart[r] += __shfl_xor(lpart[r], off, 64);
    }

    // epilogue: un-normalized bf16 partials + fp32 denominators
    const int blk = (b * NQT + qt) * NCHUNK + c;
    unsigned short* Ob = Opart + (size_t)blk * (QTILE * HD);
    #pragma unroll
    for (int n = 0; n < 4; ++n)
        #pragma unroll
        for (int r = 0; r < 4; ++r)
            Ob[(w * 16 + quad * 4 + r) * HD + n * 16 + col] = f2bf(oacc[n][r]);
    if (col == 0) {
        float* lb = Lsum + (size_t)blk * QTILE + w * 16;
        #pragma unroll
        for (int r = 0; r < 4; ++r)
            lb[quad * 4 + r] = lpart[r];
    }
}

// ---------------------------------------------------------------------------
// combine: out = sum(Opart) / sum(l).  1 thread per (row, 4 dims): uint2
// bf16 loads, float4 store.  grid 1024 x 256.  nc <= 4 chunks per row.
// ---------------------------------------------------------------------------
__global__ __launch_bounds__(256)
void combine_kernel(const unsigned short* __restrict__ Opart,
                    const float* __restrict__ Lsum,
                    float* __restrict__ out)
{
    const int gid = blockIdx.x * 256 + threadIdx.x;
    const int i   = gid >> 4;          // global row
    const int d4  = (gid & 15) * 4;    // dim group
    const int b   = i >> 11;
    const int s   = i & 2047;
    const int qt  = s >> 7;            // 128-row q tile
    const int r   = s & 127;
    const int nc  = (s >> 9) + 1;      // chunks touching this row (<=4)
    const int blk0 = (b * NQT + qt) * NCHUNK;

    float L = 0.f;
    float a0 = 0.f, a1 = 0.f, a2 = 0.f, a3 = 0.f;
    for (int cc = 0; cc < nc; ++cc) {
        L += Lsum[(size_t)(blk0 + cc) * QTILE + r];
        const uint2 u = *(const uint2*)(Opart + (size_t)(blk0 + cc) * (QTILE * HD) + r * HD + d4);
        a0 += __uint_as_float(u.x << 16);
        a1 += __uint_as_float(u.x & 0xFFFF0000u);
        a2 += __uint_as_float(u.y << 16);
        a3 += __uint_as_float(u.y & 0xFFFF0000u);
    }
    const float rL = 1.0f / L;
    float4 o; o.x = a0 * rL; o.y = a1 * rL; o.z = a2 * rL; o.w = a3 * rL;
    *(float4*)&out[(size_t)i * HD + d4] = o;
}

// ---------------------------------------------------------------------------
extern "C" void kernel_launch(void* const* d_in, const int* in_sizes, int n_in,
                              void* d_out, int out_size, void* d_ws, size_t ws_size,
                              hipStream_t stream) {
    const float* x  = (const float*)d_in[0];
    const float* Wq = (const float*)d_in[1];
    const float* bq = (const float*)d_in[2];
    const float* Wk = (const float*)d_in[3];
    const float* bk = (const float*)d_in[4];
    const float* Wv = (const float*)d_in[5];
    const float* bv = (const float*)d_in[6];
    float* out = (float*)d_out;

    unsigned short* Wt    = (unsigned short*)d_ws;        // [3][64][1024] bf16
    unsigned short* Qg    = Wt + (size_t)3 * HD * DIM;    // [16384][64] bf16 (pre-scaled)
    unsigned short* Kg    = Qg + (size_t)NROWS * HD;      // [16384][64] bf16
    unsigned short* Vtg   = Kg + (size_t)NROWS * HD;      // [8][64][2048] bf16
    unsigned short* Opart = Vtg + (size_t)BATCH * HD * SEQ;               // [512][128][64] bf16
    float* Lsum = (float*)(Opart + (size_t)BATCH * NQT * NCHUNK * QTILE * HD);  // [512][128]

    prep_w_kernel<<<dim3(16, 3), 256, 0, stream>>>(Wq, Wk, Wv, Wt);
    qkv_mfma_kernel<<<dim3(NROWS / 64), 768, 0, stream>>>(x, Wt, bq, bk, bv, Qg, Kg, Vtg);
    attn_part_kernel<<<dim3(8, 40), 512, 0, stream>>>(Qg, Kg, Vtg, Opart, Lsum);
    combine_kernel<<<dim3(NROWS * 16 / 256), 256, 0, stream>>>(Opart, Lsum, out);
}

// Round 9
// 134.567 us; speedup vs baseline: 1.7380x; 1.0082x over previous
//
#include <hip/hip_runtime.h>
#include <math.h>

#define BATCH 8
#define SEQ   2048
#define DIM   1024
#define HD    64
#define NROWS (BATCH * SEQ)   // 16384
#define CHUNK 512
#define NCHUNK 4              // SEQ / CHUNK
#define QTILE 128             // q rows per attention block
#define NQT   (SEQ / QTILE)   // 16
#define QSCALE 0.1803368801f  // 0.125 * log2(e): folded into Q so P = exp2(QK^T)

typedef __attribute__((ext_vector_type(8))) short bf16x8;  // 8 bf16 = 4 VGPRs
typedef __attribute__((ext_vector_type(4))) float f32x4;

__device__ __forceinline__ unsigned short f2bf(float f) {
    unsigned u = __float_as_uint(f);
    u = (u + 0x7FFFu + ((u >> 16) & 1u)) >> 16;   // RNE
    return (unsigned short)u;
}
// cheap half-up rounding (2 ops)
__device__ __forceinline__ unsigned short f2bf_hu(float f) {
    return (unsigned short)((__float_as_uint(f) + 0x8000u) >> 16);
}
__device__ __forceinline__ float fast_exp2(float x) {
#if __has_builtin(__builtin_amdgcn_exp2f)
    return __builtin_amdgcn_exp2f(x);
#else
    return exp2f(x);
#endif
}

// async global -> LDS DMA, 16 B per lane.  LDS dest = wave-uniform base + lane*16.
__device__ __forceinline__ void gld_lds16(const void* g, void* l) {
    __builtin_amdgcn_global_load_lds(
        (const __attribute__((address_space(1))) void*)g,
        (__attribute__((address_space(3))) void*)l, 16, 0, 0);
}

// pack 8 fp32 -> 8 bf16 (half-up) as one uint4
__device__ __forceinline__ uint4 pack_bf16x8(float4 a, float4 b) {
    uint4 o;
    o.x = ((__float_as_uint(a.x) + 0x8000u) >> 16) | ((__float_as_uint(a.y) + 0x8000u) & 0xFFFF0000u);
    o.y = ((__float_as_uint(a.z) + 0x8000u) >> 16) | ((__float_as_uint(a.w) + 0x8000u) & 0xFFFF0000u);
    o.z = ((__float_as_uint(b.x) + 0x8000u) >> 16) | ((__float_as_uint(b.y) + 0x8000u) & 0xFFFF0000u);
    o.w = ((__float_as_uint(b.z) + 0x8000u) >> 16) | ((__float_as_uint(b.w) + 0x8000u) & 0xFFFF0000u);
    return o;
}

#define CFENCE() asm volatile("" ::: "memory")
#define RAW_BAR() do { CFENCE(); __builtin_amdgcn_s_barrier(); CFENCE(); } while (0)

// Heavy-first (c,qt) schedule for attn: 28 8-tile chunks per batch dispatch
// first, light chunks backfill.  Entry = (qt << 2) | c.
__device__ __constant__ unsigned char ATTN_MAP[40] = {
    12, 16, 20, 24, 28, 32, 36, 40, 44, 48, 52, 56, 60,   // 8-tile c=0
    29, 33, 37, 41, 45, 49, 53, 57, 61,                     // 8-tile c=1
    46, 50, 54, 58, 62,                                     // 8-tile c=2
    63,                                                     // 8-tile c=3
    8, 25, 42, 59,                                          // 6-tile
    4, 21, 38, 55,                                          // 4-tile
    0, 17, 34, 51                                           // 2-tile
};

// ---------------------------------------------------------------------------
// prep_w: Wt[mat][n][k] (bf16) <- W[k][n] (fp32).  grid (16,3), block 256.
// ---------------------------------------------------------------------------
__global__ __launch_bounds__(256)
void prep_w_kernel(const float* __restrict__ Wq, const float* __restrict__ Wk,
                   const float* __restrict__ Wv, unsigned short* __restrict__ Wt)
{
    const int mat = blockIdx.y;
    const float* __restrict__ W = (mat == 0) ? Wq : (mat == 1) ? Wk : Wv;
    const int k0 = blockIdx.x * 64;
    __shared__ float T[64][65];
    const int t = threadIdx.x;
    #pragma unroll
    for (int i = 0; i < 16; ++i) {
        const int idx = t + i * 256;
        T[idx >> 6][idx & 63] = W[(size_t)(k0 + (idx >> 6)) * HD + (idx & 63)];
    }
    __syncthreads();
    const int n = t >> 2;
    const int c = t & 3;
    union { unsigned short h[16]; uint4 v[2]; } buf;
    #pragma unroll
    for (int j = 0; j < 16; ++j) buf.h[j] = f2bf(T[c * 16 + j][n]);
    unsigned short* dst = Wt + ((size_t)mat * HD + n) * DIM + k0 + c * 16;
    *(uint4*)dst       = buf.v[0];
    *(uint4*)(dst + 8) = buf.v[1];
}

// ---------------------------------------------------------------------------
// qkv_mfma v5: tile 64 rows x 192 cols (grid 256), BK=64, double-buffered,
// one barrier per iteration, counted post-compute vmcnt (round-8, kept).
// 12 waves (768 thr): wave w -> mat = w>>2, row quarter wr = w&3.
// ---------------------------------------------------------------------------
__global__ __launch_bounds__(768)
void qkv_mfma_kernel(const float* __restrict__ x,
                     const unsigned short* __restrict__ Wt,
                     const float* __restrict__ bq, const float* __restrict__ bk,
                     const float* __restrict__ bv,
                     unsigned short* __restrict__ Qg,
                     unsigned short* __restrict__ Kg,
                     unsigned short* __restrict__ Vtg)
{
    __shared__ unsigned short Xs[2][64][64];    // 16 KB bf16, swizzled chunks (key r&7)
    __shared__ unsigned short Ws[2][192][64];   // 48 KB bf16, swizzled chunks (key r&7)

    const int t    = threadIdx.x;
    const int lane = t & 63;
    const int w    = t >> 6;         // 0..11
    const int col  = lane & 15;
    const int quad = lane >> 4;
    const int mat  = w >> 2;         // 0=Q, 1=K, 2=V
    const int wr   = w & 3;          // 16-row quarter
    const int row0 = blockIdx.x * 64;

    const int r8  = lane >> 3;       // W: row within an 8-row DMA call
    const int ch8 = lane & 7;        // W: 16B chunk within row (8 chunks)
    const int wswz = (ch8 ^ r8) * 8; // W source swizzle (rbase ≡ 0 mod 8)

    f32x4 acc[4];
    #pragma unroll
    for (int i = 0; i < 4; ++i) acc[i] = (f32x4){0.f, 0.f, 0.f, 0.f};

    // X staging: threads 0..511 own (row xr, 8-float chunk xc0)
    const int xr  = t >> 3;          // 0..63
    const int xc0 = t & 7;           // 0..7
    const float* __restrict__ xrow = &x[(size_t)(row0 + xr) * DIM];

    auto stageW = [&](int it, int bb) {   // 2 calls x 8 rows = 16 rows per wave
        const int k0 = it * 64;
        #pragma unroll
        for (int ii = 0; ii < 2; ++ii) {
            const int rbase = w * 16 + ii * 8;
            gld_lds16(&Wt[(size_t)(rbase + r8) * DIM + k0 + wswz], &Ws[bb][rbase][0]);
        }
    };
    auto computeT = [&](int bb) {
        #pragma unroll
        for (int ks = 0; ks < 2; ++ks) {
            const int fswz = ((ks * 4 + quad) ^ (col & 7)) * 8;
            const bf16x8 a = *(const bf16x8*)&Xs[bb][wr * 16 + col][fswz];
            #pragma unroll
            for (int nt = 0; nt < 4; ++nt) {
                const bf16x8 b = *(const bf16x8*)&Ws[bb][mat * 64 + nt * 16 + col][fswz];
                acc[nt] = __builtin_amdgcn_mfma_f32_16x16x32_bf16(a, b, acc[nt], 0, 0, 0);
            }
        }
    };

    // ---- prologue: stage tile 0; prefetch x(1) into regs ----
    float4 xa, xb;
    stageW(0, 0);
    if (t < 512) {
        xa = *(const float4*)(xrow + xc0 * 8);
        xb = *(const float4*)(xrow + xc0 * 8 + 4);
    }
    asm volatile("s_waitcnt vmcnt(0)" ::: "memory");
    if (t < 512) {
        *(uint4*)&Xs[0][xr][(xc0 ^ (xr & 7)) * 8] = pack_bf16x8(xa, xb);
        xa = *(const float4*)(xrow + 64 + xc0 * 8);
        xb = *(const float4*)(xrow + 64 + xc0 * 8 + 4);
    }
    asm volatile("s_waitcnt lgkmcnt(0)" ::: "memory");
    RAW_BAR();   // tile 0 fully in LDS

    int buf = 0;
    for (int it = 0; it < 16; ++it) {
        if (it < 15) {
            stageW(it + 1, buf ^ 1);         // W(it+1) DMA: lands under compute
            if (t < 512) {
                // store x(it+1) from regs (loaded 1 iteration ago)
                *(uint4*)&Xs[buf ^ 1][xr][(xc0 ^ (xr & 7)) * 8] = pack_bf16x8(xa, xb);
                if (it < 14) {               // issue x(it+2): 2-deep prefetch
                    const float* xp = xrow + (it + 2) * 64;
                    xa = *(const float4*)(xp + xc0 * 8);
                    xb = *(const float4*)(xp + xc0 * 8 + 4);
                }
            }
        }
        computeT(buf);                       // tile it
        if (it < 15) {
            // post-compute wait: drain W(it+1) (+x-store lgkm), keep x(it+2)
            // loads in flight for the staging waves while it<14.
            if (w < 8 && it < 14)
                asm volatile("s_waitcnt vmcnt(2) lgkmcnt(0)" ::: "memory");
            else
                asm volatile("s_waitcnt vmcnt(0) lgkmcnt(0)" ::: "memory");
            RAW_BAR();                       // single barrier per iteration
        }
        buf ^= 1;
    }

    // Epilogue.  C layout: col = lane&15, row = quad*4 + r.
    const int b    = row0 / SEQ;
    const int s0   = (row0 % SEQ) + wr * 16 + quad * 4;
    const int grow = row0 + wr * 16 + quad * 4;
    const float* __restrict__ bias = (mat == 0) ? bq : (mat == 1) ? bk : bv;
    const float oscale = (mat == 0) ? QSCALE : 1.0f;   // fold softmax scale into Q
    #pragma unroll
    for (int nt = 0; nt < 4; ++nt) {
        const int nn = nt * 16 + col;
        const float bvv = bias[nn];
        if (mat < 2) {
            unsigned short* __restrict__ o = (mat == 0) ? Qg : Kg;
            #pragma unroll
            for (int r = 0; r < 4; ++r)
                o[(size_t)(grow + r) * HD + nn] = f2bf((acc[nt][r] + bvv) * oscale);
        } else {
            const unsigned lo = (unsigned)f2bf(acc[nt][0] + bvv) | ((unsigned)f2bf(acc[nt][1] + bvv) << 16);
            const unsigned hi = (unsigned)f2bf(acc[nt][2] + bvv) | ((unsigned)f2bf(acc[nt][3] + bvv) << 16);
            *(uint2*)&Vtg[((size_t)b * HD + nn) * SEQ + s0] = make_uint2(lo, hi);
        }
    }
}

// ---------------------------------------------------------------------------
// attn_part v5: split-key flash attention (QTILE=128, CHUNK=512, 8 waves),
// TRIPLE-buffered K/V with 2-iteration latency cover:
//   per iter: vmcnt(2) [retires stage(it), issued 2 iters ago] -> barrier ->
//   issue stage(it+2) [targets buf (it-1)%3, whose readers just passed the
//   barrier] -> compute(it).  One barrier/iter; never vmcnt(0) until tail.
// qt<4 q-tiles have a single chunk -> normalize in-register and write fp32
// out directly (no Opart/Lsum round-trip for 1/4 of rows).
// grid (8, 40): x = batch (XCD-aligned), y = heavy-first slot.  LDS 67 KB.
// ---------------------------------------------------------------------------
__global__ __launch_bounds__(512)
void attn_part_kernel(const unsigned short* __restrict__ Qg,
                      const unsigned short* __restrict__ Kg,
                      const unsigned short* __restrict__ Vtg,
                      unsigned short* __restrict__ Opart,  // [512][128][64] bf16
                      float* __restrict__ Lsum,            // [512][128]
                      float* __restrict__ out)             // [16384][64] f32
{
    const int b = blockIdx.x;
    const int code = ATTN_MAP[blockIdx.y];
    const int qt = code >> 2;
    const int c  = code & 3;

    __shared__ unsigned short Ks[3][64][64];  // [key][d], swizzled (key r&7)
    __shared__ unsigned short Vs[3][64][64];  // [d][key], swizzled
    __shared__ unsigned short Ps[8][16][76];  // per-wave P, A layout [m][key]

    const int t    = threadIdx.x;
    const int w    = t >> 6;         // 0..7
    const int lane = t & 63;
    const int col  = lane & 15;
    const int quad = lane >> 4;
    const int q0w  = qt * QTILE + w * 16;
    const size_t gq = (size_t)b * SEQ + q0w;

    const bf16x8 aq0 = *(const bf16x8*)&Qg[(gq + col) * HD + quad * 8];
    const bf16x8 aq1 = *(const bf16x8*)&Qg[(gq + col) * HD + 32 + quad * 8];

    f32x4 oacc[4];
    #pragma unroll
    for (int n = 0; n < 4; ++n) oacc[n] = (f32x4){0.f, 0.f, 0.f, 0.f};
    float lpart[4] = {0.f, 0.f, 0.f, 0.f};   // per-lane partial denominators

    const int kbeg   = c * CHUNK;
    const int kend   = min((c + 1) * CHUNK, (qt + 1) * QTILE);
    const int ntiles = (kend - kbeg + 63) >> 6;   // 2..8

    const int r8 = lane >> 3, ch = lane & 7;
    const int swzr = (ch ^ r8) * 8;
    const unsigned short* kgb = Kg  + (size_t)b * SEQ * HD;
    const unsigned short* vgb = Vtg + (size_t)b * HD * SEQ;

    // stage K tile (8 KB) + V^T tile (8 KB): 8 waves x (1 K + 1 V call) x 8 rows
    auto stageKV = [&](int it, int bb) {
        const int j0 = kbeg + it * 64;
        const int rb = w * 8;
        gld_lds16(&kgb[(size_t)(j0 + rb + r8) * HD + swzr], &Ks[bb][rb][0]);
        gld_lds16(&vgb[(size_t)(rb + r8) * SEQ + j0 + swzr], &Vs[bb][rb][0]);
    };

    // prologue: 2-deep prefetch (Q loads retire under it=0's vmcnt(2))
    stageKV(0, 0);
    if (ntiles > 1) stageKV(1, 1);

    int bufb = 0;
    for (int it = 0; it < ntiles; ++it) {
        // retire stage(it); keep stage(it+1) in flight (issued last iter,
        // or in the prologue).  Wave-uniform count.
        if (it + 1 < ntiles)
            asm volatile("s_waitcnt vmcnt(2)" ::: "memory");
        else
            asm volatile("s_waitcnt vmcnt(0)" ::: "memory");
        RAW_BAR();                      // tile `it` in LDS for every wave
        if (it + 2 < ntiles) {
            // target buf (bufb+2)%3 == (it-1)%3: its readers (compute(it-1))
            // all passed the barrier above -> safe to overwrite.
            const int tb = (bufb >= 1) ? bufb - 1 : bufb + 2;
            stageKV(it + 2, tb);
        }
        const int j0 = kbeg + it * 64;

        if (j0 <= q0w + 15) {   // wave-uniform: skip fully-masked tiles
            // scores (log2 domain: Q carries 0.125*log2e)
            f32x4 scv[4];
            #pragma unroll
            for (int nt = 0; nt < 4; ++nt) {
                const int sw0 = (quad ^ (col & 7)) * 8;
                const int sw1 = ((4 + quad) ^ (col & 7)) * 8;
                const bf16x8 bk0 = *(const bf16x8*)&Ks[bufb][nt * 16 + col][sw0];
                const bf16x8 bk1 = *(const bf16x8*)&Ks[bufb][nt * 16 + col][sw1];
                f32x4 s = __builtin_amdgcn_mfma_f32_16x16x32_bf16(aq0, bk0, (f32x4){0.f,0.f,0.f,0.f}, 0, 0, 0);
                s = __builtin_amdgcn_mfma_f32_16x16x32_bf16(aq1, bk1, s, 0, 0, 0);
                scv[nt] = s;
            }
            const bool needmask = (j0 + 63 > q0w);
            #pragma unroll
            for (int r = 0; r < 4; ++r) {
                const int row = q0w + quad * 4 + r;
                #pragma unroll
                for (int nt = 0; nt < 4; ++nt) {
                    float s = scv[nt][r];
                    if (needmask)
                        s = (j0 + nt * 16 + col <= row) ? s : -INFINITY;
                    const float p = fast_exp2(s);   // exp2(-inf) = 0 handles mask
                    lpart[r] += p;
                    Ps[w][quad * 4 + r][nt * 16 + col] = f2bf_hu(p);  // same-wave LDS
                }
            }
            // PV: O += P V
            #pragma unroll
            for (int ks = 0; ks < 2; ++ks) {
                const bf16x8 ap = *(const bf16x8*)&Ps[w][col][ks * 32 + quad * 8];
                const int fswz = ((ks * 4 + quad) ^ (col & 7)) * 8;
                #pragma unroll
                for (int n = 0; n < 4; ++n) {
                    const bf16x8 bv2 = *(const bf16x8*)&Vs[bufb][n * 16 + col][fswz];
                    oacc[n] = __builtin_amdgcn_mfma_f32_16x16x32_bf16(ap, bv2, oacc[n], 0, 0, 0);
                }
            }
        }
        bufb = (bufb == 2) ? 0 : bufb + 1;
    }

    // deferred 16-lane reduction of the denominators (once per kernel)
    #pragma unroll
    for (int r = 0; r < 4; ++r) {
        #pragma unroll
        for (int off = 1; off < 16; off <<= 1)
            lpart[r] += __shfl_xor(lpart[r], off, 64);
    }

    if (qt < 4) {
        // single-chunk q-tile: full causal range done here -> write fp32 out
        float rL[4];
        #pragma unroll
        for (int r = 0; r < 4; ++r) rL[r] = 1.0f / lpart[r];
        #pragma unroll
        for (int n = 0; n < 4; ++n)
            #pragma unroll
            for (int r = 0; r < 4; ++r)
                out[(gq + quad * 4 + r) * HD + n * 16 + col] = oacc[n][r] * rL[r];
        return;
    }

    // epilogue: un-normalized bf16 partials + fp32 denominators
    const int blk = (b * NQT + qt) * NCHUNK + c;
    unsigned short* Ob = Opart + (size_t)blk * (QTILE * HD);
    #pragma unroll
    for (int n = 0; n < 4; ++n)
        #pragma unroll
        for (int r = 0; r < 4; ++r)
            Ob[(w * 16 + quad * 4 + r) * HD + n * 16 + col] = f2bf(oacc[n][r]);
    if (col == 0) {
        float* lb = Lsum + (size_t)blk * QTILE + w * 16;
        #pragma unroll
        for (int r = 0; r < 4; ++r)
            lb[quad * 4 + r] = lpart[r];
    }
}

// ---------------------------------------------------------------------------
// combine: out = sum(Opart) / sum(l) for rows s >= 512 only (qt<4 rows are
// written directly by attn).  1 thread per (row, 4 dims); grid 768 x 256.
// ---------------------------------------------------------------------------
__global__ __launch_bounds__(256)
void combine_kernel(const unsigned short* __restrict__ Opart,
                    const float* __restrict__ Lsum,
                    float* __restrict__ out)
{
    const int gid = blockIdx.x * 256 + threadIdx.x;
    const int i   = gid >> 4;          // 0..12287 (rows with s>=512)
    const int d4  = (gid & 15) * 4;    // dim group
    const int b   = i / 1536;
    const int s   = 512 + (i - b * 1536);
    const int qt  = s >> 7;            // 128-row q tile (4..15)
    const int r   = s & 127;
    const int nc  = (s >> 9) + 1;      // chunks touching this row (2..4)
    const int blk0 = (b * NQT + qt) * NCHUNK;

    float L = 0.f;
    float a0 = 0.f, a1 = 0.f, a2 = 0.f, a3 = 0.f;
    for (int cc = 0; cc < nc; ++cc) {
        L += Lsum[(size_t)(blk0 + cc) * QTILE + r];
        const uint2 u = *(const uint2*)(Opart + (size_t)(blk0 + cc) * (QTILE * HD) + r * HD + d4);
        a0 += __uint_as_float(u.x << 16);
        a1 += __uint_as_float(u.x & 0xFFFF0000u);
        a2 += __uint_as_float(u.y << 16);
        a3 += __uint_as_float(u.y & 0xFFFF0000u);
    }
    const float rL = 1.0f / L;
    float4 o; o.x = a0 * rL; o.y = a1 * rL; o.z = a2 * rL; o.w = a3 * rL;
    *(float4*)&out[((size_t)b * SEQ + s) * HD + d4] = o;
}

// ---------------------------------------------------------------------------
extern "C" void kernel_launch(void* const* d_in, const int* in_sizes, int n_in,
                              void* d_out, int out_size, void* d_ws, size_t ws_size,
                              hipStream_t stream) {
    const float* x  = (const float*)d_in[0];
    const float* Wq = (const float*)d_in[1];
    const float* bq = (const float*)d_in[2];
    const float* Wk = (const float*)d_in[3];
    const float* bk = (const float*)d_in[4];
    const float* Wv = (const float*)d_in[5];
    const float* bv = (const float*)d_in[6];
    float* out = (float*)d_out;

    unsigned short* Wt    = (unsigned short*)d_ws;        // [3][64][1024] bf16
    unsigned short* Qg    = Wt + (size_t)3 * HD * DIM;    // [16384][64] bf16 (pre-scaled)
    unsigned short* Kg    = Qg + (size_t)NROWS * HD;      // [16384][64] bf16
    unsigned short* Vtg   = Kg + (size_t)NROWS * HD;      // [8][64][2048] bf16
    unsigned short* Opart = Vtg + (size_t)BATCH * HD * SEQ;               // [512][128][64] bf16
    float* Lsum = (float*)(Opart + (size_t)BATCH * NQT * NCHUNK * QTILE * HD);  // [512][128]

    prep_w_kernel<<<dim3(16, 3), 256, 0, stream>>>(Wq, Wk, Wv, Wt);
    qkv_mfma_kernel<<<dim3(NROWS / 64), 768, 0, stream>>>(x, Wt, bq, bk, bv, Qg, Kg, Vtg);
    attn_part_kernel<<<dim3(8, 40), 512, 0, stream>>>(Qg, Kg, Vtg, Opart, Lsum, out);
    combine_kernel<<<dim3(768), 256, 0, stream>>>(Opart, Lsum, out);
}